// Round 1
// baseline (846.474 us; speedup 1.0000x reference)
//
#include <hip/hip_runtime.h>
#include <stdint.h>

// NCA: B=8, C=16, H=W=128, hidden=128, 8 steps.
// ws layout: [0,8MB) mid state, [8MB,16MB) cur state, [16MB,+128KB) pre mask,
//            [16.25MB,+2MB) packed threefry dropout-mask bits. Needs ~19 MB ws.

#define BATCH 8
#define CH 16
#define HT 128
#define WD 128
#define HIDN 128
#define PLANE (HT*WD)             // 16384
#define IMG (CH*PLANE)            // 262144
#define NELEM (BATCH*IMG)         // 2097152
#define NPIX (BATCH*PLANE)        // 131072
#define WORDS_PER_STEP (NELEM/32) // 65536
#define NSTEPS 8

#define TX 32
#define TY 8
#define LDSH (TY+2)
#define LDSW 36

struct Keys { unsigned k[2*NSTEPS]; };

__host__ __device__ __forceinline__ unsigned rotl32u(unsigned v, int r) {
  return (v << r) | (v >> (32 - r));
}

// JAX threefry2x32 (20 rounds), verbatim structure from jax/_src/prng.py.
__host__ __device__ __forceinline__ void tf2x32(unsigned k0, unsigned k1,
                                                unsigned c0, unsigned c1,
                                                unsigned &o0, unsigned &o1) {
  const unsigned ks2 = k0 ^ k1 ^ 0x1BD11BDAu;
  unsigned x0 = c0 + k0, x1 = c1 + k1;
  x0 += x1; x1 = rotl32u(x1, 13); x1 ^= x0;
  x0 += x1; x1 = rotl32u(x1, 15); x1 ^= x0;
  x0 += x1; x1 = rotl32u(x1, 26); x1 ^= x0;
  x0 += x1; x1 = rotl32u(x1,  6); x1 ^= x0;
  x0 += k1; x1 += ks2 + 1u;
  x0 += x1; x1 = rotl32u(x1, 17); x1 ^= x0;
  x0 += x1; x1 = rotl32u(x1, 29); x1 ^= x0;
  x0 += x1; x1 = rotl32u(x1, 16); x1 ^= x0;
  x0 += x1; x1 = rotl32u(x1, 24); x1 ^= x0;
  x0 += ks2; x1 += k0 + 2u;
  x0 += x1; x1 = rotl32u(x1, 13); x1 ^= x0;
  x0 += x1; x1 = rotl32u(x1, 15); x1 ^= x0;
  x0 += x1; x1 = rotl32u(x1, 26); x1 ^= x0;
  x0 += x1; x1 = rotl32u(x1,  6); x1 ^= x0;
  x0 += k0; x1 += k1 + 3u;
  x0 += x1; x1 = rotl32u(x1, 17); x1 ^= x0;
  x0 += x1; x1 = rotl32u(x1, 29); x1 ^= x0;
  x0 += x1; x1 = rotl32u(x1, 16); x1 ^= x0;
  x0 += x1; x1 = rotl32u(x1, 24); x1 ^= x0;
  x0 += k1; x1 += ks2 + 4u;
  x0 += x1; x1 = rotl32u(x1, 13); x1 ^= x0;
  x0 += x1; x1 = rotl32u(x1, 15); x1 ^= x0;
  x0 += x1; x1 = rotl32u(x1, 26); x1 ^= x0;
  x0 += x1; x1 = rotl32u(x1,  6); x1 ^= x0;
  x0 += ks2; x1 += k0 + 5u;
  o0 = x0; o1 = x1;
}

// Precompute dropout masks for all 8 steps, packed 32 elements/word.
// Partitionable threefry: bits[e] = b1^b2 of threefry(key_step, (0, e));
// upd_mask[e] = (bits[e] >> 9) != 0  (i.e. uniform > 0.0).
__global__ __launch_bounds__(256) void mask_kernel(unsigned* __restrict__ mask,
                                                   Keys keys) {
  unsigned t = blockIdx.x * 256u + threadIdx.x;   // 8 * 65536 threads
  unsigned step = t >> 16;
  unsigned k0 = keys.k[2*step], k1 = keys.k[2*step + 1];
  unsigned base = (t & 65535u) << 5;
  unsigned word = 0u;
  #pragma unroll 4
  for (int i = 0; i < 32; ++i) {
    unsigned b1x, b2x;
    tf2x32(k0, k1, 0u, base + (unsigned)i, b1x, b2x);
    unsigned bits = b1x ^ b2x;
    word |= (((bits >> 9) != 0u) ? 1u : 0u) << i;
  }
  mask[t] = word;   // t == step*65536 + word_idx
}

// Step kernel A: pre-alive mask, perceive (id+sobelx+sobely), MLP, residual.
__global__ __launch_bounds__(256) void step_a(
    const float* __restrict__ s,
    const float* __restrict__ w1,   // [128,48]
    const float* __restrict__ b1,   // [128]
    const float* __restrict__ w2,   // [16,128]
    const float* __restrict__ b2,   // [16]
    const unsigned* __restrict__ mask,   // this step's packed mask words
    float* __restrict__ mid,
    unsigned char* __restrict__ pre) {
  __shared__ float tile[CH][LDSH][LDSW];
  const int tid = threadIdx.x;
  const int tileX = blockIdx.x, tileY = blockIdx.y, b = blockIdx.z;
  const int x0t = tileX * TX, y0t = tileY * TY;

  // cooperative halo load (zeros outside image == SAME zero padding)
  const int TOT = CH * LDSH * LDSW;   // 5760
  for (int i = tid; i < TOT; i += 256) {
    int c  = i / (LDSH * LDSW);
    int r  = i % (LDSH * LDSW);
    int ly = r / LDSW, lx = r % LDSW;
    int gy = y0t + ly - 1, gx = x0t + lx - 1;
    float v = 0.f;
    if ((unsigned)gy < HT && (unsigned)gx < WD)
      v = s[b * IMG + c * PLANE + gy * WD + gx];
    tile[c][ly][lx] = v;
  }
  __syncthreads();

  const int tx = tid & 31, ty = tid >> 5;
  const int lx = tx + 1, ly = ty + 1;
  const int gx = x0t + tx, gy = y0t + ty;

  float p[48];
  float premax = -1e30f;
  #pragma unroll
  for (int c = 0; c < CH; ++c) {
    float a00 = tile[c][ly-1][lx-1], a01 = tile[c][ly-1][lx], a02 = tile[c][ly-1][lx+1];
    float a10 = tile[c][ly  ][lx-1], a11 = tile[c][ly  ][lx], a12 = tile[c][ly  ][lx+1];
    float a20 = tile[c][ly+1][lx-1], a21 = tile[c][ly+1][lx], a22 = tile[c][ly+1][lx+1];
    p[c]      = a11;
    p[16 + c] = (a02 - a00) + 2.f * (a12 - a10) + (a22 - a20);   // sobel_x (corr)
    p[32 + c] = (a20 - a00) + 2.f * (a21 - a01) + (a22 - a02);   // sobel_y (corr)
    if (c == 3) {
      float m0 = fmaxf(fmaxf(a00, a01), fmaxf(a02, a10));
      float m1 = fmaxf(fmaxf(a11, a12), fmaxf(a20, a21));
      premax = fmaxf(fmaxf(m0, m1), a22);
    }
  }

  float dx[16];
  #pragma unroll
  for (int o = 0; o < 16; ++o) dx[o] = b2[o];

  for (int hid = 0; hid < HIDN; ++hid) {      // uniform indices -> s_load weights
    const float* wr = w1 + hid * 48;
    float t0 = 0.f, t1 = 0.f, t2 = 0.f, t3 = 0.f;
    #pragma unroll
    for (int c = 0; c < 48; c += 4) {
      t0 = fmaf(p[c + 0], wr[c + 0], t0);
      t1 = fmaf(p[c + 1], wr[c + 1], t1);
      t2 = fmaf(p[c + 2], wr[c + 2], t2);
      t3 = fmaf(p[c + 3], wr[c + 3], t3);
    }
    float t = ((t0 + t1) + (t2 + t3)) + b1[hid];
    t = fmaxf(t, 0.f);
    #pragma unroll
    for (int o = 0; o < 16; ++o)
      dx[o] = fmaf(t, w2[o * HIDN + hid], dx[o]);
  }

  pre[b * PLANE + gy * WD + gx] = (premax > 0.1f) ? 1 : 0;

  #pragma unroll
  for (int o = 0; o < 16; ++o) {
    float d = fminf(fmaxf(dx[o], -5.f), 5.f);
    unsigned mw = mask[((b * 16 + o) * HT + gy) * 4 + tileX];
    float v = p[o] + (((mw >> tx) & 1u) ? d : 0.f);
    mid[b * IMG + o * PLANE + gy * WD + gx] = v;
  }
}

// Step kernel B: post-alive maxpool on mid, apply pre&post.
__global__ __launch_bounds__(256) void step_b(
    const float* __restrict__ mid,
    const unsigned char* __restrict__ pre,
    float* __restrict__ out) {
  int t = blockIdx.x * 256 + threadIdx.x;   // 131072 pixels
  int b = t >> 14;
  int r = t & 16383;
  int y = r >> 7, x = r & 127;
  const float* m3 = mid + b * IMG + 3 * PLANE;
  float mx = -1e30f;
  #pragma unroll
  for (int dy = -1; dy <= 1; ++dy) {
    int yy = y + dy; if ((unsigned)yy >= HT) continue;
    #pragma unroll
    for (int dxx = -1; dxx <= 1; ++dxx) {
      int xx = x + dxx; if ((unsigned)xx >= WD) continue;
      mx = fmaxf(mx, m3[yy * WD + xx]);
    }
  }
  float f = ((mx > 0.1f) && pre[t]) ? 1.f : 0.f;
  #pragma unroll
  for (int c = 0; c < CH; ++c) {
    float v = mid[b * IMG + c * PLANE + r];
    out[b * IMG + c * PLANE + r] = v * f;
  }
}

extern "C" void kernel_launch(void* const* d_in, const int* in_sizes, int n_in,
                              void* d_out, int out_size, void* d_ws, size_t ws_size,
                              hipStream_t stream) {
  const float* x  = (const float*)d_in[0];
  const float* w1 = (const float*)d_in[1];
  const float* b1 = (const float*)d_in[2];
  const float* w2 = (const float*)d_in[3];
  const float* b2 = (const float*)d_in[4];
  float* out = (float*)d_out;

  char* ws = (char*)d_ws;
  float* mid = (float*)ws;
  float* cur = (float*)(ws + (size_t)NELEM * 4);
  unsigned char* pre = (unsigned char*)(ws + 2 * (size_t)NELEM * 4);
  unsigned* mask = (unsigned*)(ws + 2 * (size_t)NELEM * 4 + 256 * 1024);

  // keys = jax.random.split(key(42), 8), partitionable/fold-like:
  // keys[j] = threefry2x32((0,42), (0, j))  (both outputs form the key pair)
  Keys keys;
  for (int j = 0; j < NSTEPS; ++j) {
    unsigned a, b;
    tf2x32(0u, 42u, 0u, (unsigned)j, a, b);
    keys.k[2 * j] = a; keys.k[2 * j + 1] = b;
  }

  mask_kernel<<<(NSTEPS * WORDS_PER_STEP) / 256, 256, 0, stream>>>(mask, keys);

  const float* src = x;
  for (int s = 0; s < NSTEPS; ++s) {
    step_a<<<dim3(WD / TX, HT / TY, BATCH), 256, 0, stream>>>(
        src, w1, b1, w2, b2, mask + s * WORDS_PER_STEP, mid, pre);
    float* dst = (s == NSTEPS - 1) ? out : cur;
    step_b<<<NPIX / 256, 256, 0, stream>>>(mid, pre, dst);
    src = cur;
  }
}

// Round 2
// 723.132 us; speedup vs baseline: 1.1706x; 1.1706x over previous
//
#include <hip/hip_runtime.h>
#include <stdint.h>

// NCA: B=8, C=16, H=W=128, hidden=128, 8 steps.
// ws layout: [0,8MB) mid, [8MB,16MB) cur, [16MB,+128KB) pre,
//            [+2MB) packed threefry mask bits, [+32KB) wpack. ~18.5 MB.

#define BATCH 8
#define CH 16
#define HT 128
#define WD 128
#define HIDN 128
#define PLANE (HT*WD)
#define IMG (CH*PLANE)
#define NELEM (BATCH*IMG)
#define NPIX (BATCH*PLANE)
#define WORDS_PER_STEP (NELEM/32)
#define NSTEPS 8

#define TX 32
#define TY 8
#define LDSH (TY+2)
#define LDSW 36

struct Keys { unsigned k[2*NSTEPS]; };

__host__ __device__ __forceinline__ unsigned rotl32u(unsigned v, int r) {
  return (v << r) | (v >> (32 - r));
}

// JAX threefry2x32 (20 rounds).
__host__ __device__ __forceinline__ void tf2x32(unsigned k0, unsigned k1,
                                                unsigned c0, unsigned c1,
                                                unsigned &o0, unsigned &o1) {
  const unsigned ks2 = k0 ^ k1 ^ 0x1BD11BDAu;
  unsigned x0 = c0 + k0, x1 = c1 + k1;
  x0 += x1; x1 = rotl32u(x1, 13); x1 ^= x0;
  x0 += x1; x1 = rotl32u(x1, 15); x1 ^= x0;
  x0 += x1; x1 = rotl32u(x1, 26); x1 ^= x0;
  x0 += x1; x1 = rotl32u(x1,  6); x1 ^= x0;
  x0 += k1; x1 += ks2 + 1u;
  x0 += x1; x1 = rotl32u(x1, 17); x1 ^= x0;
  x0 += x1; x1 = rotl32u(x1, 29); x1 ^= x0;
  x0 += x1; x1 = rotl32u(x1, 16); x1 ^= x0;
  x0 += x1; x1 = rotl32u(x1, 24); x1 ^= x0;
  x0 += ks2; x1 += k0 + 2u;
  x0 += x1; x1 = rotl32u(x1, 13); x1 ^= x0;
  x0 += x1; x1 = rotl32u(x1, 15); x1 ^= x0;
  x0 += x1; x1 = rotl32u(x1, 26); x1 ^= x0;
  x0 += x1; x1 = rotl32u(x1,  6); x1 ^= x0;
  x0 += k0; x1 += k1 + 3u;
  x0 += x1; x1 = rotl32u(x1, 17); x1 ^= x0;
  x0 += x1; x1 = rotl32u(x1, 29); x1 ^= x0;
  x0 += x1; x1 = rotl32u(x1, 16); x1 ^= x0;
  x0 += x1; x1 = rotl32u(x1, 24); x1 ^= x0;
  x0 += k1; x1 += ks2 + 4u;
  x0 += x1; x1 = rotl32u(x1, 13); x1 ^= x0;
  x0 += x1; x1 = rotl32u(x1, 15); x1 ^= x0;
  x0 += x1; x1 = rotl32u(x1, 26); x1 ^= x0;
  x0 += x1; x1 = rotl32u(x1,  6); x1 ^= x0;
  x0 += ks2; x1 += k0 + 5u;
  o0 = x0; o1 = x1;
}

__global__ __launch_bounds__(256) void mask_kernel(unsigned* __restrict__ mask,
                                                   Keys keys) {
  unsigned t = blockIdx.x * 256u + threadIdx.x;
  unsigned step = t >> 16;
  unsigned k0 = keys.k[2*step], k1 = keys.k[2*step + 1];
  unsigned base = (t & 65535u) << 5;
  unsigned word = 0u;
  #pragma unroll 4
  for (int i = 0; i < 32; ++i) {
    unsigned b1x, b2x;
    tf2x32(k0, k1, 0u, base + (unsigned)i, b1x, b2x);
    unsigned bits = b1x ^ b2x;
    word |= (((bits >> 9) != 0u) ? 1u : 0u) << i;
  }
  mask[t] = word;
}

// Pack weights: wpack[h][0..47] = w1[h][:], wpack[h][48+o] = w2[o][h].
// One contiguous 256B row per hidden unit -> pure sequential s_load stream.
__global__ __launch_bounds__(256) void wpack_kernel(
    const float* __restrict__ w1, const float* __restrict__ w2,
    float* __restrict__ wpack) {
  int t = blockIdx.x * 256 + threadIdx.x;   // 8192
  int h = t >> 6, j = t & 63;
  wpack[t] = (j < 48) ? w1[h * 48 + j] : w2[(j - 48) * HIDN + h];
}

// Step kernel A: pre-alive mask, perceive, MLP, residual.
// __launch_bounds__(256,2): grid is 512 blocks = 2 blocks/CU max anyway;
// allow up to ~256 VGPR so p[48]+dx[16] stay in registers (round 1: 48 VGPR
// => scratch spills => 18% VALUBusy).
__global__ __launch_bounds__(256, 2) void step_a(
    const float* __restrict__ s,
    const float* __restrict__ wpack,  // [128][64]
    const float* __restrict__ b1,     // [128]
    const float* __restrict__ b2,     // [16]
    const unsigned* __restrict__ mask,
    float* __restrict__ mid,
    unsigned char* __restrict__ pre) {
  __shared__ float tile[CH][LDSH][LDSW];
  const int tid = threadIdx.x;
  const int tileX = blockIdx.x, tileY = blockIdx.y, b = blockIdx.z;
  const int x0t = tileX * TX, y0t = tileY * TY;

  const int TOT = CH * LDSH * LDSW;   // 5760
  for (int i = tid; i < TOT; i += 256) {
    int c  = i / (LDSH * LDSW);
    int r  = i % (LDSH * LDSW);
    int ly = r / LDSW, lx = r % LDSW;
    int gy = y0t + ly - 1, gx = x0t + lx - 1;
    float v = 0.f;
    if ((unsigned)gy < HT && (unsigned)gx < WD)
      v = s[b * IMG + c * PLANE + gy * WD + gx];
    tile[c][ly][lx] = v;
  }
  __syncthreads();

  const int tx = tid & 31, ty = tid >> 5;
  const int lx = tx + 1, ly = ty + 1;
  const int gx = x0t + tx, gy = y0t + ty;

  float p[48];
  float premax = -1e30f;
  #pragma unroll
  for (int c = 0; c < CH; ++c) {
    float a00 = tile[c][ly-1][lx-1], a01 = tile[c][ly-1][lx], a02 = tile[c][ly-1][lx+1];
    float a10 = tile[c][ly  ][lx-1], a11 = tile[c][ly  ][lx], a12 = tile[c][ly  ][lx+1];
    float a20 = tile[c][ly+1][lx-1], a21 = tile[c][ly+1][lx], a22 = tile[c][ly+1][lx+1];
    p[c]      = a11;
    p[16 + c] = (a02 - a00) + 2.f * (a12 - a10) + (a22 - a20);
    p[32 + c] = (a20 - a00) + 2.f * (a21 - a01) + (a22 - a02);
    if (c == 3) {
      float m0 = fmaxf(fmaxf(a00, a01), fmaxf(a02, a10));
      float m1 = fmaxf(fmaxf(a11, a12), fmaxf(a20, a21));
      premax = fmaxf(fmaxf(m0, m1), a22);
    }
  }

  float dx[16];
  #pragma unroll
  for (int o = 0; o < 16; ++o) dx[o] = b2[o];

  #pragma unroll 2
  for (int hid = 0; hid < HIDN; ++hid) {
    const float* wr = wpack + hid * 64;   // uniform -> s_load, sequential
    float t0 = 0.f, t1 = 0.f, t2 = 0.f, t3 = 0.f;
    #pragma unroll
    for (int c = 0; c < 48; c += 4) {
      t0 = fmaf(p[c + 0], wr[c + 0], t0);
      t1 = fmaf(p[c + 1], wr[c + 1], t1);
      t2 = fmaf(p[c + 2], wr[c + 2], t2);
      t3 = fmaf(p[c + 3], wr[c + 3], t3);
    }
    float t = ((t0 + t1) + (t2 + t3)) + b1[hid];
    t = fmaxf(t, 0.f);
    #pragma unroll
    for (int o = 0; o < 16; ++o)
      dx[o] = fmaf(t, wr[48 + o], dx[o]);
  }

  pre[b * PLANE + gy * WD + gx] = (premax > 0.1f) ? 1 : 0;

  #pragma unroll
  for (int o = 0; o < 16; ++o) {
    float d = fminf(fmaxf(dx[o], -5.f), 5.f);
    unsigned mw = mask[((b * 16 + o) * HT + gy) * 4 + tileX];
    float v = p[o] + (((mw >> tx) & 1u) ? d : 0.f);
    mid[b * IMG + o * PLANE + gy * WD + gx] = v;
  }
}

// Step kernel B: post-alive maxpool + apply pre&post, float4-vectorized.
__global__ __launch_bounds__(256) void step_b(
    const float* __restrict__ mid,
    const unsigned char* __restrict__ pre,
    float* __restrict__ out) {
  int t = blockIdx.x * 256 + threadIdx.x;   // NPIX/4 = 32768 threads
  int b = t >> 12;
  int r = t & 4095;          // quad index in plane
  int y = r >> 5;
  int x0 = (r & 31) * 4;
  const float* m3 = mid + b * IMG + 3 * PLANE;

  float col[6];
  #pragma unroll
  for (int j = 0; j < 6; ++j) {
    int xx = x0 - 1 + j;
    float m = -1e30f;
    if ((unsigned)xx < WD) {
      #pragma unroll
      for (int dy = -1; dy <= 1; ++dy) {
        int yy = y + dy;
        if ((unsigned)yy < HT) m = fmaxf(m, m3[yy * WD + xx]);
      }
    }
    col[j] = m;
  }

  const unsigned char* pr = pre + b * PLANE + y * WD + x0;
  float f[4];
  #pragma unroll
  for (int i = 0; i < 4; ++i) {
    float mx = fmaxf(fmaxf(col[i], col[i + 1]), col[i + 2]);
    f[i] = ((mx > 0.1f) && pr[i]) ? 1.f : 0.f;
  }

  #pragma unroll
  for (int c = 0; c < CH; ++c) {
    const float4 v = *(const float4*)&mid[b * IMG + c * PLANE + y * WD + x0];
    float4 w;
    w.x = v.x * f[0]; w.y = v.y * f[1]; w.z = v.z * f[2]; w.w = v.w * f[3];
    *(float4*)&out[b * IMG + c * PLANE + y * WD + x0] = w;
  }
}

extern "C" void kernel_launch(void* const* d_in, const int* in_sizes, int n_in,
                              void* d_out, int out_size, void* d_ws, size_t ws_size,
                              hipStream_t stream) {
  const float* x  = (const float*)d_in[0];
  const float* w1 = (const float*)d_in[1];
  const float* b1 = (const float*)d_in[2];
  const float* w2 = (const float*)d_in[3];
  const float* b2 = (const float*)d_in[4];
  float* out = (float*)d_out;

  char* ws = (char*)d_ws;
  float* mid = (float*)ws;
  float* cur = (float*)(ws + (size_t)NELEM * 4);
  unsigned char* pre = (unsigned char*)(ws + 2 * (size_t)NELEM * 4);
  unsigned* mask = (unsigned*)(ws + 2 * (size_t)NELEM * 4 + 256 * 1024);
  float* wpack = (float*)(ws + 2 * (size_t)NELEM * 4 + 256 * 1024
                             + (size_t)NSTEPS * WORDS_PER_STEP * 4);

  // keys = jax.random.split(key(42), 8): keys[j] = threefry2x32((0,42),(0,j))
  Keys keys;
  for (int j = 0; j < NSTEPS; ++j) {
    unsigned a, b;
    tf2x32(0u, 42u, 0u, (unsigned)j, a, b);
    keys.k[2 * j] = a; keys.k[2 * j + 1] = b;
  }

  mask_kernel<<<(NSTEPS * WORDS_PER_STEP) / 256, 256, 0, stream>>>(mask, keys);
  wpack_kernel<<<HIDN * 64 / 256, 256, 0, stream>>>(w1, w2, wpack);

  const float* src = x;
  for (int s = 0; s < NSTEPS; ++s) {
    step_a<<<dim3(WD / TX, HT / TY, BATCH), 256, 0, stream>>>(
        src, wpack, b1, b2, mask + s * WORDS_PER_STEP, mid, pre);
    float* dst = (s == NSTEPS - 1) ? out : cur;
    step_b<<<(NPIX / 4) / 256, 256, 0, stream>>>(mid, pre, dst);
    src = cur;
  }
}

// Round 3
// 668.167 us; speedup vs baseline: 1.2669x; 1.0823x over previous
//
#include <hip/hip_runtime.h>
#include <stdint.h>

// NCA: B=8, C=16, H=W=128, hidden=128, 8 steps.
// ws layout: [0,8MB) mid, [8MB,16MB) cur, [16MB,+128KB) pre,
//            [+2MB) packed threefry mask bits, [+32KB) wpack. ~18.5 MB.

#define BATCH 8
#define CH 16
#define HT 128
#define WD 128
#define HIDN 128
#define PLANE (HT*WD)
#define IMG (CH*PLANE)
#define NELEM (BATCH*IMG)
#define NPIX (BATCH*PLANE)
#define WORDS_PER_STEP (NELEM/32)
#define NSTEPS 8

struct Keys { unsigned k[2*NSTEPS]; };

__host__ __device__ __forceinline__ unsigned rotl32u(unsigned v, int r) {
  return (v << r) | (v >> (32 - r));
}

// JAX threefry2x32 (20 rounds).
__host__ __device__ __forceinline__ void tf2x32(unsigned k0, unsigned k1,
                                                unsigned c0, unsigned c1,
                                                unsigned &o0, unsigned &o1) {
  const unsigned ks2 = k0 ^ k1 ^ 0x1BD11BDAu;
  unsigned x0 = c0 + k0, x1 = c1 + k1;
  x0 += x1; x1 = rotl32u(x1, 13); x1 ^= x0;
  x0 += x1; x1 = rotl32u(x1, 15); x1 ^= x0;
  x0 += x1; x1 = rotl32u(x1, 26); x1 ^= x0;
  x0 += x1; x1 = rotl32u(x1,  6); x1 ^= x0;
  x0 += k1; x1 += ks2 + 1u;
  x0 += x1; x1 = rotl32u(x1, 17); x1 ^= x0;
  x0 += x1; x1 = rotl32u(x1, 29); x1 ^= x0;
  x0 += x1; x1 = rotl32u(x1, 16); x1 ^= x0;
  x0 += x1; x1 = rotl32u(x1, 24); x1 ^= x0;
  x0 += ks2; x1 += k0 + 2u;
  x0 += x1; x1 = rotl32u(x1, 13); x1 ^= x0;
  x0 += x1; x1 = rotl32u(x1, 15); x1 ^= x0;
  x0 += x1; x1 = rotl32u(x1, 26); x1 ^= x0;
  x0 += x1; x1 = rotl32u(x1,  6); x1 ^= x0;
  x0 += k0; x1 += k1 + 3u;
  x0 += x1; x1 = rotl32u(x1, 17); x1 ^= x0;
  x0 += x1; x1 = rotl32u(x1, 29); x1 ^= x0;
  x0 += x1; x1 = rotl32u(x1, 16); x1 ^= x0;
  x0 += x1; x1 = rotl32u(x1, 24); x1 ^= x0;
  x0 += k1; x1 += ks2 + 4u;
  x0 += x1; x1 = rotl32u(x1, 13); x1 ^= x0;
  x0 += x1; x1 = rotl32u(x1, 15); x1 ^= x0;
  x0 += x1; x1 = rotl32u(x1, 26); x1 ^= x0;
  x0 += x1; x1 = rotl32u(x1,  6); x1 ^= x0;
  x0 += ks2; x1 += k0 + 5u;
  o0 = x0; o1 = x1;
}

__global__ __launch_bounds__(256) void mask_kernel(unsigned* __restrict__ mask,
                                                   Keys keys) {
  unsigned t = blockIdx.x * 256u + threadIdx.x;
  unsigned step = t >> 16;
  unsigned k0 = keys.k[2*step], k1 = keys.k[2*step + 1];
  unsigned base = (t & 65535u) << 5;
  unsigned word = 0u;
  #pragma unroll 4
  for (int i = 0; i < 32; ++i) {
    unsigned b1x, b2x;
    tf2x32(k0, k1, 0u, base + (unsigned)i, b1x, b2x);
    unsigned bits = b1x ^ b2x;
    word |= (((bits >> 9) != 0u) ? 1u : 0u) << i;
  }
  mask[t] = word;
}

// wpack[h][0..47] = w1[h][:], wpack[h][48+o] = w2[o][h].
__global__ __launch_bounds__(256) void wpack_kernel(
    const float* __restrict__ w1, const float* __restrict__ w2,
    float* __restrict__ wpack) {
  int t = blockIdx.x * 256 + threadIdx.x;   // 8192
  int h = t >> 6, j = t & 63;
  wpack[t] = (j < 48) ? w1[h * 48 + j] : w2[(j - 48) * HIDN + h];
}

// Step kernel A. 512 threads = 256 pixels (32x8 tile) x 2 hidden-halves.
// Weights live in LDS (broadcast ds_read_b128); perceive reads global
// directly (state is L2-resident). Partial dx combined via padded LDS.
__global__ __launch_bounds__(512, 4) void step_a(
    const float* __restrict__ s,
    const float* __restrict__ wpack,  // [128][64]
    const float* __restrict__ b1,     // [128]
    const float* __restrict__ b2,     // [16]
    const unsigned* __restrict__ mask,
    float* __restrict__ mid,
    unsigned char* __restrict__ pre) {
  __shared__ float wlds[HIDN][64];    // 32 KB
  __shared__ float b1lds[HIDN];       // 0.5 KB
  __shared__ float red[256][17];      // 17.4 KB (pad 17 -> conflict-free)

  const int tid = threadIdx.x;
  const int pix = tid & 255;
  const int half = __builtin_amdgcn_readfirstlane(tid >> 8);  // wave-uniform
  const int tileX = blockIdx.x, tileY = blockIdx.y, b = blockIdx.z;
  const int tx = pix & 31, ty = pix >> 5;
  const int gx = tileX * 32 + tx, gy = tileY * 8 + ty;

  // stage weights into LDS (coalesced float4)
  {
    const float4* src4 = (const float4*)wpack;
    float4* dst4 = (float4*)&wlds[0][0];
    #pragma unroll
    for (int i = 0; i < 4; ++i) dst4[tid + 512 * i] = src4[tid + 512 * i];
    if (tid < HIDN) b1lds[tid] = b1[tid];
  }
  __syncthreads();

  // ---- perceive: direct global 3x3 (predicated borders) ----
  const float* sb = s + b * IMG;
  const int ctr = gy * WD + gx;
  bool yu = (gy > 0), yd = (gy < HT - 1), xl = (gx > 0), xr = (gx < WD - 1);

  float p[48];
  float premax;
  #pragma unroll
  for (int c = 0; c < CH; ++c) {
    const float* sc = sb + c * PLANE + ctr;
    float a11 = sc[0];
    float a00 = (yu && xl) ? sc[-WD - 1] : 0.f;
    float a01 = yu         ? sc[-WD]     : 0.f;
    float a02 = (yu && xr) ? sc[-WD + 1] : 0.f;
    float a10 = xl         ? sc[-1]      : 0.f;
    float a12 = xr         ? sc[1]       : 0.f;
    float a20 = (yd && xl) ? sc[WD - 1]  : 0.f;
    float a21 = yd         ? sc[WD]      : 0.f;
    float a22 = (yd && xr) ? sc[WD + 1]  : 0.f;
    p[c]      = a11;
    p[16 + c] = (a02 - a00) + 2.f * (a12 - a10) + (a22 - a20);
    p[32 + c] = (a20 - a00) + 2.f * (a21 - a01) + (a22 - a02);
    if (c == 3) {
      float m0 = fmaxf(fmaxf(a00, a01), fmaxf(a02, a10));
      float m1 = fmaxf(fmaxf(a11, a12), fmaxf(a20, a21));
      premax = fmaxf(fmaxf(m0, m1), a22);
    }
  }

  // ---- MLP over this thread's 64 hidden units ----
  float dx[16];
  #pragma unroll
  for (int o = 0; o < 16; ++o) dx[o] = 0.f;

  const int hbase = half * 64;
  for (int i = 0; i < 64; ++i) {
    const int hid = hbase + i;
    const float4* w4 = (const float4*)&wlds[hid][0];   // uniform -> broadcast
    float t0 = 0.f, t1 = 0.f, t2 = 0.f, t3 = 0.f;
    #pragma unroll
    for (int j = 0; j < 12; ++j) {
      float4 w = w4[j];
      t0 = fmaf(p[4 * j + 0], w.x, t0);
      t1 = fmaf(p[4 * j + 1], w.y, t1);
      t2 = fmaf(p[4 * j + 2], w.z, t2);
      t3 = fmaf(p[4 * j + 3], w.w, t3);
    }
    float h = ((t0 + t1) + (t2 + t3)) + b1lds[hid];
    h = fmaxf(h, 0.f);
    #pragma unroll
    for (int j = 0; j < 4; ++j) {
      float4 w = w4[12 + j];
      dx[4 * j + 0] = fmaf(h, w.x, dx[4 * j + 0]);
      dx[4 * j + 1] = fmaf(h, w.y, dx[4 * j + 1]);
      dx[4 * j + 2] = fmaf(h, w.z, dx[4 * j + 2]);
      dx[4 * j + 3] = fmaf(h, w.w, dx[4 * j + 3]);
    }
  }

  // ---- combine halves, residual, masks ----
  if (half == 0) {
    #pragma unroll
    for (int o = 0; o < 16; ++o) red[pix][o] = dx[o];
  }
  __syncthreads();
  if (half == 0) {
    pre[b * PLANE + gy * WD + gx] = (premax > 0.1f) ? 1 : 0;
  } else {
    #pragma unroll
    for (int o = 0; o < 16; ++o) {
      float d = dx[o] + red[pix][o] + b2[o];
      d = fminf(fmaxf(d, -5.f), 5.f);
      unsigned mw = mask[((b * 16 + o) * HT + gy) * 4 + tileX];
      float v = p[o] + (((mw >> tx) & 1u) ? d : 0.f);
      mid[b * IMG + o * PLANE + gy * WD + gx] = v;
    }
  }
}

// Step kernel B: post-alive maxpool + apply pre&post, float4-vectorized.
__global__ __launch_bounds__(256) void step_b(
    const float* __restrict__ mid,
    const unsigned char* __restrict__ pre,
    float* __restrict__ out) {
  int t = blockIdx.x * 256 + threadIdx.x;   // NPIX/4 threads
  int b = t >> 12;
  int r = t & 4095;
  int y = r >> 5;
  int x0 = (r & 31) * 4;
  const float* m3 = mid + b * IMG + 3 * PLANE;

  float col[6];
  #pragma unroll
  for (int j = 0; j < 6; ++j) {
    int xx = x0 - 1 + j;
    float m = -1e30f;
    if ((unsigned)xx < WD) {
      #pragma unroll
      for (int dy = -1; dy <= 1; ++dy) {
        int yy = y + dy;
        if ((unsigned)yy < HT) m = fmaxf(m, m3[yy * WD + xx]);
      }
    }
    col[j] = m;
  }

  const unsigned char* pr = pre + b * PLANE + y * WD + x0;
  float f[4];
  #pragma unroll
  for (int i = 0; i < 4; ++i) {
    float mx = fmaxf(fmaxf(col[i], col[i + 1]), col[i + 2]);
    f[i] = ((mx > 0.1f) && pr[i]) ? 1.f : 0.f;
  }

  #pragma unroll
  for (int c = 0; c < CH; ++c) {
    const float4 v = *(const float4*)&mid[b * IMG + c * PLANE + y * WD + x0];
    float4 w;
    w.x = v.x * f[0]; w.y = v.y * f[1]; w.z = v.z * f[2]; w.w = v.w * f[3];
    *(float4*)&out[b * IMG + c * PLANE + y * WD + x0] = w;
  }
}

extern "C" void kernel_launch(void* const* d_in, const int* in_sizes, int n_in,
                              void* d_out, int out_size, void* d_ws, size_t ws_size,
                              hipStream_t stream) {
  const float* x  = (const float*)d_in[0];
  const float* w1 = (const float*)d_in[1];
  const float* b1 = (const float*)d_in[2];
  const float* w2 = (const float*)d_in[3];
  const float* b2 = (const float*)d_in[4];
  float* out = (float*)d_out;

  char* ws = (char*)d_ws;
  float* mid = (float*)ws;
  float* cur = (float*)(ws + (size_t)NELEM * 4);
  unsigned char* pre = (unsigned char*)(ws + 2 * (size_t)NELEM * 4);
  unsigned* mask = (unsigned*)(ws + 2 * (size_t)NELEM * 4 + 256 * 1024);
  float* wpack = (float*)(ws + 2 * (size_t)NELEM * 4 + 256 * 1024
                             + (size_t)NSTEPS * WORDS_PER_STEP * 4);

  // keys = jax.random.split(key(42), 8): keys[j] = threefry2x32((0,42),(0,j))
  Keys keys;
  for (int j = 0; j < NSTEPS; ++j) {
    unsigned a, b;
    tf2x32(0u, 42u, 0u, (unsigned)j, a, b);
    keys.k[2 * j] = a; keys.k[2 * j + 1] = b;
  }

  mask_kernel<<<(NSTEPS * WORDS_PER_STEP) / 256, 256, 0, stream>>>(mask, keys);
  wpack_kernel<<<HIDN * 64 / 256, 256, 0, stream>>>(w1, w2, wpack);

  const float* src = x;
  for (int s = 0; s < NSTEPS; ++s) {
    step_a<<<dim3(WD / 32, HT / 8, BATCH), 512, 0, stream>>>(
        src, wpack, b1, b2, mask + s * WORDS_PER_STEP, mid, pre);
    float* dst = (s == NSTEPS - 1) ? out : cur;
    step_b<<<(NPIX / 4) / 256, 256, 0, stream>>>(mid, pre, dst);
    src = cur;
  }
}